// Round 20
// baseline (634.433 us; speedup 1.0000x reference)
//
#include <hip/hip_runtime.h>
#include <hip/hip_bf16.h>
#include <stdint.h>

typedef __attribute__((ext_vector_type(8))) short short8;
typedef __attribute__((ext_vector_type(4))) float f32x4;
typedef __attribute__((ext_vector_type(4))) float float4v;
typedef __attribute__((ext_vector_type(4))) int int4v;

#define MDIM 8192
#define NDIM 11008
#define KDIM 4096
#define BKI  64                /* i8 K-tile */
#define NTI  (KDIM / BKI)      /* 64 K-tiles */
#define NBMI (MDIM / 128)      /* 64 */
#define NBNI (NDIM / 128)      /* 86 */
#define NXB  (MDIM / 16)       /* 512 x row-blocks */
#define NC16 (NDIM / 16)       /* 688 w col-blocks */

// ws layout (bytes)
#define AQ_OFF  0ull                                  /* A fragment-linear, 32 MB */
#define WQ_OFF  ((size_t)MDIM * KDIM)                 /* B fragment-linear, 43 MB */
#define SXR_OFF (WQ_OFF + (size_t)NDIM * KDIM)
#define SWC_OFF (SXR_OFF + (size_t)MDIM * 4)
#define WS_NEED (SWC_OFF + (size_t)NDIM * 4)          /* ~78.7 MB */

static __device__ __forceinline__ unsigned short f2bf(float f) {
  union { float f; unsigned int u; } v;
  v.f = f;
  unsigned int r = v.u + 0x7FFFu + ((v.u >> 16) & 1u);
  return (unsigned short)(r >> 16);
}

// ---------------- pass 1 (fused) ---------------------------------------------
// blocks [0, NXB): r18-verified per-row x quant -> fragment-linear aqf.
// blocks [NXB, NXB+NC16): 16 w-cols -> per-col smin re-quant (r18 numerics) ->
//   fragment-linear wqf (r11-verified layout):
//   wqf[((c16*NTI+kt)<<10)+l*16] = B[c16*16+(l&15)][kt*64+(l>>4)*16 ..+15]
__global__ __launch_bounds__(256) void prep_all(
    const float* __restrict__ x, char* __restrict__ aqf, float* __restrict__ sxr,
    const int* __restrict__ qw, const float* __restrict__ scale,
    char* __restrict__ wqf, float* __restrict__ swc) {
  const int t = threadIdx.x;
  if (blockIdx.x < NXB) {
    __shared__ char sq[16 * 272];
    const int r16 = blockIdx.x;
    const int row = t >> 4;              // 0..15
    const int seg = t & 15;
    const float* rowp = x + ((size_t)(r16 * 16 + row)) * KDIM;
    float amax = 0.f;
    for (int j = 0; j < 16; ++j) {
      const float* p = rowp + j * 256 + seg * 16;
#pragma unroll
      for (int c = 0; c < 4; ++c) {
        float4v v = *(const float4v*)(p + c * 4);
#pragma unroll
        for (int e = 0; e < 4; ++e) amax = fmaxf(amax, fabsf(v[e]));
      }
    }
#pragma unroll
    for (int d = 1; d < 16; d <<= 1) amax = fmaxf(amax, __shfl_xor(amax, d));
    amax = fmaxf(amax, 1e-20f);
    if (seg == 0) sxr[r16 * 16 + row] = amax * (1.0f / 127.0f);
    const float inv = 127.0f / amax;
    for (int j = 0; j < 16; ++j) {
      const float* p = rowp + j * 256 + seg * 16;
      int4v o;
#pragma unroll
      for (int c = 0; c < 4; ++c) {
        float4v v = *(const float4v*)(p + c * 4);
        unsigned int r = 0;
#pragma unroll
        for (int e = 0; e < 4; ++e) {
          int q = __float2int_rn(v[e] * inv);
          r |= ((unsigned int)(q & 255)) << (8 * e);
        }
        o[c] = (int)r;
      }
      *(int4v*)(sq + row * 272 + seg * 16) = o;
      __syncthreads();
      {
        const int ktl = t >> 6;
        const int l = t & 63;
        int4v vv = *(const int4v*)(sq + (l & 15) * 272 + ktl * 64 + (l >> 4) * 16);
        *(int4v*)(aqf + (((size_t)r16 * NTI + j * 4 + ktl) << 10) + l * 16) = vv;
      }
      __syncthreads();
    }
  } else {
    const int c16 = blockIdx.x - NXB;    // 0..687
    __shared__ float sgl[256];           // [col16][g]
    sgl[t] = scale[(size_t)(c16 * 16 + (t >> 4)) * 16 + (t & 15)];
    __syncthreads();
    const int lane = t & 63;
    const int l15 = lane & 15;           // col within block
    const int lh = lane >> 4;            // k granule 0..3
    const int ktl = t >> 6;              // 0..3
    float smin = sgl[l15 * 16];
#pragma unroll
    for (int g = 1; g < 16; ++g) smin = fminf(smin, sgl[l15 * 16 + g]);
    if (t < 16) {
      float sm = sgl[t * 16];
#pragma unroll
      for (int g = 1; g < 16; ++g) sm = fminf(sm, sgl[t * 16 + g]);
      swc[c16 * 16 + t] = 1.0f / sm;
    }
    const int* colp = qw + (size_t)(c16 * 16 + l15) * KDIM;
    for (int i = 0; i < 16; ++i) {       // group i -> kts i*4..i*4+3
      const int kt = i * 4 + ktl;
      const float ratio = smin / sgl[l15 * 16 + i];
      const int* src = colp + kt * 64 + lh * 16;
      int4v v[4];
#pragma unroll
      for (int c = 0; c < 4; ++c) v[c] = *(const int4v*)(src + c * 4);
      int4v o;
#pragma unroll
      for (int c = 0; c < 4; ++c) {
        unsigned int r = 0;
#pragma unroll
        for (int e = 0; e < 4; ++e) {
          int q2 = __float2int_rn((float)v[c][e] * ratio);
          r |= ((unsigned int)(q2 & 255)) << (8 * e);
        }
        o[c] = (int)r;
      }
      *(int4v*)(wqf + (((size_t)c16 * NTI + kt) << 10) + lane * 16) = o;
    }
  }
}

// ---------------- pass 2: 128x128 pure-i8 GEMM, ZERO LDS / ZERO barriers -----
// Both operands fragment-linear in global -> every load is one contiguous
// 1KB wave load direct to registers. Each wave = independent FIFO pipeline:
// per tile issue [A(t+1)x4, B(t+1)x4], vmcnt(8) (drains tile t's 8), 16 MFMA.
// 2x intra-block dup per operand absorbed by L1/L2 (same lines).
__global__ __launch_bounds__(256, 3) void gemm_i8(
    const char* __restrict__ aqf, const char* __restrict__ wqf,
    const float* __restrict__ sxr, const float* __restrict__ swc,
    const float* __restrict__ bias, float* __restrict__ out)
{
  const int t = threadIdx.x;
  const int lane = t & 63;
  const int w = t >> 6;        // wave 0..3
  const int wr = w >> 1;       // 0..1  (A 64-row half)
  const int wc = w & 1;        // 0..1  (B 64-col half)
  const int lh = lane >> 4;    // 0..3
  const int l15 = lane & 15;

  // XCD-bijective swizzle: 5504 = 8 * 688
  const int bid = blockIdx.x;
  const int swz = (bid & 7) * (NBMI * NBNI / 8) + (bid >> 3);
  const int bm = swz / NBNI;
  const int bn = swz % NBNI;

  const char* aF = aqf + (((size_t)(bm * 8 + wr * 4) * NTI) << 10) + lane * 16;
  const char* bF = wqf + (((size_t)(bn * 8 + wc * 4) * NTI) << 10) + lane * 16;

  int4v acci[4][4];
#pragma unroll
  for (int m = 0; m < 4; ++m)
#pragma unroll
    for (int n = 0; n < 4; ++n) acci[m][n] = (int4v){0, 0, 0, 0};

#define ALOAD(ABUF, kt) {                                                      \
  _Pragma("unroll")                                                            \
  for (int m = 0; m < 4; ++m)                                                  \
    ABUF[m] = *(const int4v*)(aF + (((size_t)m * NTI + (kt)) << 10)); }

#define BLOAD(BBUF, kt) {                                                      \
  _Pragma("unroll")                                                            \
  for (int n = 0; n < 4; ++n)                                                  \
    BBUF[n] = *(const int4v*)(bF + (((size_t)n * NTI + (kt)) << 10)); }

#define VMW(N) asm volatile("s_waitcnt vmcnt(" N ")" ::: "memory");

// tile t: issue A(t+1),B(t+1) into the NEXT sets; vmcnt(8) drains tile t's
// own 8 loads; 16 MFMA on the CURRENT sets. No LDS, no barrier.
#define TILE(kt, AC, BC, AN, BN_, DOLOAD, WAITN) {                             \
  if (DOLOAD) { ALOAD(AN, (kt) + 1); BLOAD(BN_, (kt) + 1); }                   \
  __builtin_amdgcn_sched_barrier(0);                                           \
  VMW(WAITN)                                                                   \
  __builtin_amdgcn_sched_barrier(0);                                           \
  __builtin_amdgcn_s_setprio(1);                                               \
  _Pragma("unroll")                                                            \
  for (int m = 0; m < 4; ++m)                                                  \
    _Pragma("unroll")                                                          \
    for (int n = 0; n < 4; ++n)                                                \
      acci[m][n] = __builtin_amdgcn_mfma_i32_16x16x64_i8(AC[m], BC[n],         \
                                                         acci[m][n], 0, 0, 0); \
  __builtin_amdgcn_s_setprio(0);                                               \
}

  int4v A0f[4], B0f[4], A1f[4], B1f[4];

  // prologue: tile 0's 8 loads
  ALOAD(A0f, 0);
  BLOAD(B0f, 0);
  __builtin_amdgcn_sched_barrier(0);

  for (int kt = 0; kt < NTI - 2; kt += 2) {
    TILE(kt,     A0f, B0f, A1f, B1f, 1, "8")
    TILE(kt + 1, A1f, B1f, A0f, B0f, 1, "8")
  }
  TILE(NTI - 2, A0f, B0f, A1f, B1f, 1, "8")
  TILE(NTI - 1, A1f, B1f, A0f, B0f, 0, "0")

  // epilogue: out = acci * sxr[row] * swc[col] + bias
  float swv[4], bias_v[4];
#pragma unroll
  for (int n = 0; n < 4; ++n) {
    const int col = bn * 128 + wc * 64 + n * 16 + l15;
    swv[n] = swc[col];
    bias_v[n] = bias[col];
  }
#pragma unroll
  for (int m = 0; m < 4; ++m) {
    const int row0 = bm * 128 + wr * 64 + m * 16 + lh * 4;
    float4v sxm = *(const float4v*)(sxr + row0);
#pragma unroll
    for (int n = 0; n < 4; ++n) {
      const int col = bn * 128 + wc * 64 + n * 16 + l15;
      const float s_ = swv[n];
      const float bv_ = bias_v[n];
#pragma unroll
      for (int j = 0; j < 4; ++j)
        out[(size_t)(row0 + j) * NDIM + col] =
            (float)acci[m][n][j] * (sxm[j] * s_) + bv_;
    }
  }
#undef TILE
#undef VMW
#undef BLOAD
#undef ALOAD
}

// ---------------- fallback: fused single-pass (round-1 kernel) ----------------
__global__ __launch_bounds__(256, 2) void clinear_fused(
    const float* __restrict__ x,
    const int* __restrict__ qw,
    const float* __restrict__ scale,
    const float* __restrict__ bias,
    float* __restrict__ out)
{
  __shared__ unsigned char ldsA[128 * 64 * 2];
  __shared__ unsigned char ldsB[128 * 64 * 2];

  const int t = threadIdx.x;
  const int lane = t & 63;
  const int wave = t >> 6;
  const int wr = wave >> 1;
  const int wc = wave & 1;

  const int NBN = NDIM / 128;
  const int bid = blockIdx.x;
  const int cpx = ((MDIM / 128) * NBN) >> 3;
  const int swz = (bid & 7) * cpx + (bid >> 3);
  const int bm = swz / NBN;
  const int bn = swz % NBN;

  const int srow = t >> 1;
  const int shalf = t & 1;
  const float* aptr = x  + (size_t)(bm * 128 + srow) * KDIM + shalf * 32;
  const int*   bptr = qw + (size_t)(bn * 128 + srow) * KDIM + shalf * 32;
  const float* sptr = scale + (size_t)(bn * 128 + srow) * (KDIM / 256);
  const int arx = srow & 7;

  f32x4 acc[4][4];
#pragma unroll
  for (int i = 0; i < 4; ++i)
#pragma unroll
    for (int j = 0; j < 4; ++j)
      acc[i][j] = (f32x4){0.f, 0.f, 0.f, 0.f};

  float bias_v[4];
#pragma unroll
  for (int n = 0; n < 4; ++n)
    bias_v[n] = bias[bn * 128 + wc * 64 + n * 16 + (lane & 15)];

  for (int kt = 0; kt < KDIM / 64; ++kt) {
    const int k0 = kt * 64;
    float4v av[8];
    int4v   bv[8];
#pragma unroll
    for (int j = 0; j < 8; ++j) av[j] = *(const float4v*)(aptr + k0 + 4 * j);
#pragma unroll
    for (int j = 0; j < 8; ++j) bv[j] = *(const int4v*)(bptr + k0 + 4 * j);
    const float inv = 1.0f / sptr[k0 >> 8];

    __syncthreads();
#pragma unroll
    for (int c = 0; c < 4; ++c) {
      short8 pa, pb;
#pragma unroll
      for (int e = 0; e < 8; ++e) {
        const int v = c * 8 + e;
        pa[e] = (short)f2bf(av[v >> 2][v & 3]);
        pb[e] = (short)f2bf((float)bv[v >> 2][v & 3] * inv);
      }
      const int cc = shalf * 4 + c;
      *(short8*)(ldsA + srow * 128 + ((cc ^ arx) << 4)) = pa;
      *(short8*)(ldsB + srow * 128 + ((cc ^ arx) << 4)) = pb;
    }
    __syncthreads();

    short8 af[4][2], bfr[4][2];
#pragma unroll
    for (int m = 0; m < 4; ++m) {
      const int r = wr * 64 + m * 16 + (lane & 15);
      const int rx = r & 7;
#pragma unroll
      for (int ks = 0; ks < 2; ++ks) {
        const int ch = ks * 4 + (lane >> 4);
        af[m][ks] = *(const short8*)(ldsA + r * 128 + ((ch ^ rx) << 4));
      }
    }
#pragma unroll
    for (int n = 0; n < 4; ++n) {
      const int r = wc * 64 + n * 16 + (lane & 15);
      const int rx = r & 7;
#pragma unroll
      for (int ks = 0; ks < 2; ++ks) {
        const int ch = ks * 4 + (lane >> 4);
        bfr[n][ks] = *(const short8*)(ldsB + r * 128 + ((ch ^ rx) << 4));
      }
    }
#pragma unroll
    for (int ks = 0; ks < 2; ++ks)
#pragma unroll
      for (int m = 0; m < 4; ++m)
#pragma unroll
        for (int n = 0; n < 4; ++n)
          acc[m][n] = __builtin_amdgcn_mfma_f32_16x16x32_bf16(
              af[m][ks], bfr[n][ks], acc[m][n], 0, 0, 0);
  }

#pragma unroll
  for (int m = 0; m < 4; ++m) {
    const int row0 = bm * 128 + wr * 64 + m * 16 + (lane >> 4) * 4;
#pragma unroll
    for (int n = 0; n < 4; ++n) {
      const int col = bn * 128 + wc * 64 + n * 16 + (lane & 15);
      const float bv_ = bias_v[n];
#pragma unroll
      for (int j = 0; j < 4; ++j)
        out[(size_t)(row0 + j) * NDIM + col] = acc[m][n][j] + bv_;
    }
  }
}

extern "C" void kernel_launch(void* const* d_in, const int* in_sizes, int n_in,
                              void* d_out, int out_size, void* d_ws, size_t ws_size,
                              hipStream_t stream) {
  const float* x     = (const float*)d_in[0];
  const int*   qw    = (const int*)d_in[1];
  const float* scale = (const float*)d_in[2];
  const float* bias  = (const float*)d_in[3];
  float* out = (float*)d_out;

  if (ws_size >= WS_NEED) {
    char*  aqf = (char*)d_ws + AQ_OFF;
    char*  wqf = (char*)d_ws + WQ_OFF;
    float* sxr = (float*)((char*)d_ws + SXR_OFF);
    float* swc = (float*)((char*)d_ws + SWC_OFF);
    hipLaunchKernelGGL(prep_all, dim3(NXB + NC16), dim3(256), 0, stream,
                       x, aqf, sxr, qw, scale, wqf, swc);
    hipLaunchKernelGGL(gemm_i8, dim3(NBMI * NBNI), dim3(256), 0, stream,
                       aqf, wqf, sxr, swc, bias, out);
  } else {
    hipLaunchKernelGGL(clinear_fused, dim3((MDIM / 128) * (NDIM / 128)), dim3(256),
                       0, stream, x, qw, scale, bias, out);
  }
}

// Round 21
// 562.993 us; speedup vs baseline: 1.1269x; 1.1269x over previous
//
#include <hip/hip_runtime.h>
#include <hip/hip_bf16.h>
#include <stdint.h>

typedef __attribute__((ext_vector_type(8))) short short8;
typedef __attribute__((ext_vector_type(4))) float f32x4;
typedef __attribute__((ext_vector_type(4))) float float4v;
typedef __attribute__((ext_vector_type(4))) int int4v;

#define MDIM 8192
#define NDIM 11008
#define KDIM 4096
#define BKI  64                /* i8 K-tile */
#define NTI  (KDIM / BKI)      /* 64 K-tiles */
#define NBMI (MDIM / 128)      /* 64 */
#define NBNI (NDIM / 128)      /* 86 */
#define NXB  (MDIM / 16)       /* 512 x row-blocks */
#define NC16 (NDIM / 16)       /* 688 w col-blocks */

// ws layout (bytes)
#define AQ_OFF  0ull                                  /* A fragment-linear, 32 MB */
#define WQ_OFF  ((size_t)MDIM * KDIM)                 /* B fragment-linear, 43 MB */
#define SXR_OFF (WQ_OFF + (size_t)NDIM * KDIM)
#define SWC_OFF (SXR_OFF + (size_t)MDIM * 4)
#define WS_NEED (SWC_OFF + (size_t)NDIM * 4)          /* ~78.7 MB */

static __device__ __forceinline__ unsigned short f2bf(float f) {
  union { float f; unsigned int u; } v;
  v.f = f;
  unsigned int r = v.u + 0x7FFFu + ((v.u >> 16) & 1u);
  return (unsigned short)(r >> 16);
}

#define GLDS16(g, l) __builtin_amdgcn_global_load_lds(                         \
    (const __attribute__((address_space(1))) void*)(g),                        \
    (__attribute__((address_space(3))) void*)(l), 16, 0, 0)

// ---------------- pass 1 (fused) — r20-verified (absmax 0.09375) -------------
__global__ __launch_bounds__(256) void prep_all(
    const float* __restrict__ x, char* __restrict__ aqf, float* __restrict__ sxr,
    const int* __restrict__ qw, const float* __restrict__ scale,
    char* __restrict__ wqf, float* __restrict__ swc) {
  const int t = threadIdx.x;
  if (blockIdx.x < NXB) {
    __shared__ char sq[16 * 272];
    const int r16 = blockIdx.x;
    const int row = t >> 4;              // 0..15
    const int seg = t & 15;
    const float* rowp = x + ((size_t)(r16 * 16 + row)) * KDIM;
    float amax = 0.f;
    for (int j = 0; j < 16; ++j) {
      const float* p = rowp + j * 256 + seg * 16;
#pragma unroll
      for (int c = 0; c < 4; ++c) {
        float4v v = *(const float4v*)(p + c * 4);
#pragma unroll
        for (int e = 0; e < 4; ++e) amax = fmaxf(amax, fabsf(v[e]));
      }
    }
#pragma unroll
    for (int d = 1; d < 16; d <<= 1) amax = fmaxf(amax, __shfl_xor(amax, d));
    amax = fmaxf(amax, 1e-20f);
    if (seg == 0) sxr[r16 * 16 + row] = amax * (1.0f / 127.0f);
    const float inv = 127.0f / amax;
    for (int j = 0; j < 16; ++j) {
      const float* p = rowp + j * 256 + seg * 16;
      int4v o;
#pragma unroll
      for (int c = 0; c < 4; ++c) {
        float4v v = *(const float4v*)(p + c * 4);
        unsigned int r = 0;
#pragma unroll
        for (int e = 0; e < 4; ++e) {
          int q = __float2int_rn(v[e] * inv);
          r |= ((unsigned int)(q & 255)) << (8 * e);
        }
        o[c] = (int)r;
      }
      *(int4v*)(sq + row * 272 + seg * 16) = o;
      __syncthreads();
      {
        const int ktl = t >> 6;
        const int l = t & 63;
        int4v vv = *(const int4v*)(sq + (l & 15) * 272 + ktl * 64 + (l >> 4) * 16);
        *(int4v*)(aqf + (((size_t)r16 * NTI + j * 4 + ktl) << 10) + l * 16) = vv;
      }
      __syncthreads();
    }
  } else {
    const int c16 = blockIdx.x - NXB;    // 0..687
    __shared__ float sgl[256];           // [col16][g]
    sgl[t] = scale[(size_t)(c16 * 16 + (t >> 4)) * 16 + (t & 15)];
    __syncthreads();
    const int lane = t & 63;
    const int l15 = lane & 15;
    const int lh = lane >> 4;
    const int ktl = t >> 6;
    float smin = sgl[l15 * 16];
#pragma unroll
    for (int g = 1; g < 16; ++g) smin = fminf(smin, sgl[l15 * 16 + g]);
    if (t < 16) {
      float sm = sgl[t * 16];
#pragma unroll
      for (int g = 1; g < 16; ++g) sm = fminf(sm, sgl[t * 16 + g]);
      swc[c16 * 16 + t] = 1.0f / sm;
    }
    const int* colp = qw + (size_t)(c16 * 16 + l15) * KDIM;
    for (int i = 0; i < 16; ++i) {
      const int kt = i * 4 + ktl;
      const float ratio = smin / sgl[l15 * 16 + i];
      const int* src = colp + kt * 64 + lh * 16;
      int4v v[4];
#pragma unroll
      for (int c = 0; c < 4; ++c) v[c] = *(const int4v*)(src + c * 4);
      int4v o;
#pragma unroll
      for (int c = 0; c < 4; ++c) {
        unsigned int r = 0;
#pragma unroll
        for (int e = 0; e < 4; ++e) {
          int q2 = __float2int_rn((float)v[c][e] * ratio);
          r |= ((unsigned int)(q2 & 255)) << (8 * e);
        }
        o[c] = (int)r;
      }
      *(int4v*)(wqf + (((size_t)c16 * NTI + kt) << 10) + lane * 16) = o;
    }
  }
}

// ---------------- pass 2: 128x128 pure-i8 GEMM, shared fragment-linear LDS ---
// Both operands fragment-linear in global. Staging: GLDS with CONTIGUOUS 1KB
// per-wave source (lane-adjacent, no r14 scatter) and LINEAR LDS dest (no
// swizzle). ds_read_b128 of a fragment = contiguous 1KB wave read -> ZERO
// conflicts (r12). Each block-tile fetched ONCE (16KB) -> L2 traffic halves
// vs r20's register-direct dup. 3-deep LDS (48KB, 3 blocks/CU); distance-2
// staging; per-tile vmcnt(4)+barrier (FIFO-exact); tail 4 -> 0.
__global__ __launch_bounds__(256, 3) void gemm_i8(
    const char* __restrict__ aqf, const char* __restrict__ wqf,
    const float* __restrict__ sxr, const float* __restrict__ swc,
    const float* __restrict__ bias, float* __restrict__ out)
{
  __shared__ unsigned char lds[49152];   // [3 bufs][16KB: A strips 0-7, B strips 0-7]

  const int t = threadIdx.x;
  const int lane = t & 63;
  const int w = t >> 6;        // wave 0..3
  const int wr = w >> 1;       // 0..1  (A 64-row half)
  const int wc = w & 1;        // 0..1  (B 64-col half)
  const int lh = lane >> 4;    // 0..3
  const int l15 = lane & 15;

  // XCD-bijective swizzle: 5504 = 8 * 688
  const int bid = blockIdx.x;
  const int swz = (bid & 7) * (NBMI * NBNI / 8) + (bid >> 3);
  const int bm = swz / NBNI;
  const int bn = swz % NBNI;

  // staging sources: wave w owns A strips {2w, 2w+1} and B strips {2w, 2w+1};
  // each (strip, kt) is one contiguous 1KB block; per-lane addr = base + lane*16.
  const char* aS0 = aqf + (((size_t)(bm * 8 + 2 * w) * NTI) << 10) + lane * 16;
  const char* aS1 = aS0 + ((size_t)NTI << 10);
  const char* bS0 = wqf + (((size_t)(bn * 8 + 2 * w) * NTI) << 10) + lane * 16;
  const char* bS1 = bS0 + ((size_t)NTI << 10);
  // wave-uniform LDS dest bases (GLDS adds lane*16)
  const int aD0 = (2 * w) * 1024, aD1 = (2 * w + 1) * 1024;
  const int bD0 = 8192 + (2 * w) * 1024, bD1 = 8192 + (2 * w + 1) * 1024;

  int4v acci[4][4];
#pragma unroll
  for (int m = 0; m < 4; ++m)
#pragma unroll
    for (int n = 0; n < 4; ++n) acci[m][n] = (int4v){0, 0, 0, 0};

#define STAGE(buf, kt) {                                                       \
  GLDS16(aS0 + ((size_t)(kt) << 10), lds + (buf) * 16384 + aD0);               \
  GLDS16(aS1 + ((size_t)(kt) << 10), lds + (buf) * 16384 + aD1);               \
  GLDS16(bS0 + ((size_t)(kt) << 10), lds + (buf) * 16384 + bD0);               \
  GLDS16(bS1 + ((size_t)(kt) << 10), lds + (buf) * 16384 + bD1); }

#define RD_A(buf, m) (*(const int4v*)(lds + (buf) * 16384 +                    \
                      (wr * 4 + (m)) * 1024 + lane * 16))
#define RD_B(buf, n) (*(const int4v*)(lds + (buf) * 16384 + 8192 +             \
                      (wc * 4 + (n)) * 1024 + lane * 16))

#define VMW(N) asm volatile("s_waitcnt vmcnt(" N ")" ::: "memory");

// tile kt (buf = kt%3): issue stage(kt+2) into buf (kt+2)%3; 8 ds_read;
// 16 MFMA; vmcnt(4) drains (kt+1)'s stage before the publish barrier.
#define TILE(buf, kt, DOSTAGE, WAITN, DOBAR) {                                 \
  if (DOSTAGE) STAGE(((buf) + 2) % 3, (kt) + 2);                               \
  __builtin_amdgcn_sched_barrier(0);                                           \
  int4v a[4], b[4];                                                            \
  _Pragma("unroll")                                                            \
  for (int m = 0; m < 4; ++m) a[m] = RD_A(buf, m);                             \
  _Pragma("unroll")                                                            \
  for (int n = 0; n < 4; ++n) b[n] = RD_B(buf, n);                             \
  __builtin_amdgcn_s_setprio(1);                                               \
  _Pragma("unroll")                                                            \
  for (int m = 0; m < 4; ++m)                                                  \
    _Pragma("unroll")                                                          \
    for (int n = 0; n < 4; ++n)                                                \
      acci[m][n] = __builtin_amdgcn_mfma_i32_16x16x64_i8(a[m], b[n],           \
                                                         acci[m][n], 0, 0, 0); \
  __builtin_amdgcn_s_setprio(0);                                               \
  VMW(WAITN)                                                                   \
  if (DOBAR) __builtin_amdgcn_s_barrier(); }

  // prologue: stage tiles 0,1 (4+4 loads/wave); drain tile 0's; publish
  STAGE(0, 0);
  STAGE(1, 1);
  __builtin_amdgcn_sched_barrier(0);
  VMW("4")
  __builtin_amdgcn_s_barrier();

  // steady: 60 tiles in 20 groups of 3 (bufs 0,1,2); stages kt+2..kt+4 <= 63
  for (int kt = 0; kt < NTI - 4; kt += 3) {
    TILE(0, kt,     1, "4", 1)
    TILE(1, kt + 1, 1, "4", 1)
    TILE(2, kt + 2, 1, "4", 1)
  }
  // peeled tail: kt=60(buf0,stage 62), 61(buf1,stage 63), 62(buf2), 63(buf0)
  TILE(0, NTI - 4, 1, "4", 1)
  TILE(1, NTI - 3, 1, "4", 1)
  TILE(2, NTI - 2, 0, "0", 1)
  TILE(0, NTI - 1, 0, "0", 0)

  // epilogue: out = acci * sxr[row] * swc[col] + bias
  float swv[4], bias_v[4];
#pragma unroll
  for (int n = 0; n < 4; ++n) {
    const int col = bn * 128 + wc * 64 + n * 16 + l15;
    swv[n] = swc[col];
    bias_v[n] = bias[col];
  }
#pragma unroll
  for (int m = 0; m < 4; ++m) {
    const int row0 = bm * 128 + wr * 64 + m * 16 + lh * 4;
    float4v sxm = *(const float4v*)(sxr + row0);
#pragma unroll
    for (int n = 0; n < 4; ++n) {
      const int col = bn * 128 + wc * 64 + n * 16 + l15;
      const float s_ = swv[n];
      const float bv_ = bias_v[n];
#pragma unroll
      for (int j = 0; j < 4; ++j)
        out[(size_t)(row0 + j) * NDIM + col] =
            (float)acci[m][n][j] * (sxm[j] * s_) + bv_;
    }
  }
#undef TILE
#undef VMW
#undef RD_A
#undef RD_B
#undef STAGE
}

// ---------------- fallback: fused single-pass (round-1 kernel) ----------------
__global__ __launch_bounds__(256, 2) void clinear_fused(
    const float* __restrict__ x,
    const int* __restrict__ qw,
    const float* __restrict__ scale,
    const float* __restrict__ bias,
    float* __restrict__ out)
{
  __shared__ unsigned char ldsA[128 * 64 * 2];
  __shared__ unsigned char ldsB[128 * 64 * 2];

  const int t = threadIdx.x;
  const int lane = t & 63;
  const int wave = t >> 6;
  const int wr = wave >> 1;
  const int wc = wave & 1;

  const int NBN = NDIM / 128;
  const int bid = blockIdx.x;
  const int cpx = ((MDIM / 128) * NBN) >> 3;
  const int swz = (bid & 7) * cpx + (bid >> 3);
  const int bm = swz / NBN;
  const int bn = swz % NBN;

  const int srow = t >> 1;
  const int shalf = t & 1;
  const float* aptr = x  + (size_t)(bm * 128 + srow) * KDIM + shalf * 32;
  const int*   bptr = qw + (size_t)(bn * 128 + srow) * KDIM + shalf * 32;
  const float* sptr = scale + (size_t)(bn * 128 + srow) * (KDIM / 256);
  const int arx = srow & 7;

  f32x4 acc[4][4];
#pragma unroll
  for (int i = 0; i < 4; ++i)
#pragma unroll
    for (int j = 0; j < 4; ++j)
      acc[i][j] = (f32x4){0.f, 0.f, 0.f, 0.f};

  float bias_v[4];
#pragma unroll
  for (int n = 0; n < 4; ++n)
    bias_v[n] = bias[bn * 128 + wc * 64 + n * 16 + (lane & 15)];

  for (int kt = 0; kt < KDIM / 64; ++kt) {
    const int k0 = kt * 64;
    float4v av[8];
    int4v   bv[8];
#pragma unroll
    for (int j = 0; j < 8; ++j) av[j] = *(const float4v*)(aptr + k0 + 4 * j);
#pragma unroll
    for (int j = 0; j < 8; ++j) bv[j] = *(const int4v*)(bptr + k0 + 4 * j);
    const float inv = 1.0f / sptr[k0 >> 8];

    __syncthreads();
#pragma unroll
    for (int c = 0; c < 4; ++c) {
      short8 pa, pb;
#pragma unroll
      for (int e = 0; e < 8; ++e) {
        const int v = c * 8 + e;
        pa[e] = (short)f2bf(av[v >> 2][v & 3]);
        pb[e] = (short)f2bf((float)bv[v >> 2][v & 3] * inv);
      }
      const int cc = shalf * 4 + c;
      *(short8*)(ldsA + srow * 128 + ((cc ^ arx) << 4)) = pa;
      *(short8*)(ldsB + srow * 128 + ((cc ^ arx) << 4)) = pb;
    }
    __syncthreads();

    short8 af[4][2], bfr[4][2];
#pragma unroll
    for (int m = 0; m < 4; ++m) {
      const int r = wr * 64 + m * 16 + (lane & 15);
      const int rx = r & 7;
#pragma unroll
      for (int ks = 0; ks < 2; ++ks) {
        const int ch = ks * 4 + (lane >> 4);
        af[m][ks] = *(const short8*)(ldsA + r * 128 + ((ch ^ rx) << 4));
      }
    }
#pragma unroll
    for (int n = 0; n < 4; ++n) {
      const int r = wc * 64 + n * 16 + (lane & 15);
      const int rx = r & 7;
#pragma unroll
      for (int ks = 0; ks < 2; ++ks) {
        const int ch = ks * 4 + (lane >> 4);
        bfr[n][ks] = *(const short8*)(ldsB + r * 128 + ((ch ^ rx) << 4));
      }
    }
#pragma unroll
    for (int ks = 0; ks < 2; ++ks)
#pragma unroll
      for (int m = 0; m < 4; ++m)
#pragma unroll
        for (int n = 0; n < 4; ++n)
          acc[m][n] = __builtin_amdgcn_mfma_f32_16x16x32_bf16(
              af[m][ks], bfr[n][ks], acc[m][n], 0, 0, 0);
  }

#pragma unroll
  for (int m = 0; m < 4; ++m) {
    const int row0 = bm * 128 + wr * 64 + m * 16 + (lane >> 4) * 4;
#pragma unroll
    for (int n = 0; n < 4; ++n) {
      const int col = bn * 128 + wc * 64 + n * 16 + (lane & 15);
      const float bv_ = bias_v[n];
#pragma unroll
      for (int j = 0; j < 4; ++j)
        out[(size_t)(row0 + j) * NDIM + col] = acc[m][n][j] + bv_;
    }
  }
}

extern "C" void kernel_launch(void* const* d_in, const int* in_sizes, int n_in,
                              void* d_out, int out_size, void* d_ws, size_t ws_size,
                              hipStream_t stream) {
  const float* x     = (const float*)d_in[0];
  const int*   qw    = (const int*)d_in[1];
  const float* scale = (const float*)d_in[2];
  const float* bias  = (const float*)d_in[3];
  float* out = (float*)d_out;

  if (ws_size >= WS_NEED) {
    char*  aqf = (char*)d_ws + AQ_OFF;
    char*  wqf = (char*)d_ws + WQ_OFF;
    float* sxr = (float*)((char*)d_ws + SXR_OFF);
    float* swc = (float*)((char*)d_ws + SWC_OFF);
    hipLaunchKernelGGL(prep_all, dim3(NXB + NC16), dim3(256), 0, stream,
                       x, aqf, sxr, qw, scale, wqf, swc);
    hipLaunchKernelGGL(gemm_i8, dim3(NBMI * NBNI), dim3(256), 0, stream,
                       aqf, wqf, sxr, swc, bias, out);
  } else {
    hipLaunchKernelGGL(clinear_fused, dim3((MDIM / 128) * (NDIM / 128)), dim3(256),
                       0, stream, x, qw, scale, bias, out);
  }
}

// Round 22
// 436.736 us; speedup vs baseline: 1.4527x; 1.2891x over previous
//
#include <hip/hip_runtime.h>
#include <hip/hip_bf16.h>
#include <stdint.h>

typedef __attribute__((ext_vector_type(8))) short short8;
typedef __attribute__((ext_vector_type(4))) float f32x4;
typedef __attribute__((ext_vector_type(4))) float float4v;
typedef __attribute__((ext_vector_type(4))) int int4v;

#define MDIM 8192
#define NDIM 11008
#define KDIM 4096
#define BKI  64                /* i8 K-tile */
#define NTI  (KDIM / BKI)      /* 64 K-tiles */
#define NBM2 (MDIM / 256)      /* 32 */
#define NBNI (NDIM / 128)      /* 86 */
#define NXB  (MDIM / 16)       /* 512 x row-blocks */
#define NC16 (NDIM / 16)       /* 688 w col-blocks */

// ws layout (bytes)
#define AQ_OFF  0ull                                  /* A fragment-linear, 32 MB */
#define WQ_OFF  ((size_t)MDIM * KDIM)                 /* B fragment-linear, 43 MB */
#define SXR_OFF (WQ_OFF + (size_t)NDIM * KDIM)
#define SWC_OFF (SXR_OFF + (size_t)MDIM * 4)
#define WS_NEED (SWC_OFF + (size_t)NDIM * 4)          /* ~78.7 MB */

static __device__ __forceinline__ unsigned short f2bf(float f) {
  union { float f; unsigned int u; } v;
  v.f = f;
  unsigned int r = v.u + 0x7FFFu + ((v.u >> 16) & 1u);
  return (unsigned short)(r >> 16);
}

#define GLDS16(g, l) __builtin_amdgcn_global_load_lds(                         \
    (const __attribute__((address_space(1))) void*)(g),                        \
    (__attribute__((address_space(3))) void*)(l), 16, 0, 0)

// ---------------- pass 1 (fused) — r20-verified (absmax 0.09375) -------------
__global__ __launch_bounds__(256) void prep_all(
    const float* __restrict__ x, char* __restrict__ aqf, float* __restrict__ sxr,
    const int* __restrict__ qw, const float* __restrict__ scale,
    char* __restrict__ wqf, float* __restrict__ swc) {
  const int t = threadIdx.x;
  if (blockIdx.x < NXB) {
    __shared__ char sq[16 * 272];
    const int r16 = blockIdx.x;
    const int row = t >> 4;              // 0..15
    const int seg = t & 15;
    const float* rowp = x + ((size_t)(r16 * 16 + row)) * KDIM;
    float amax = 0.f;
    for (int j = 0; j < 16; ++j) {
      const float* p = rowp + j * 256 + seg * 16;
#pragma unroll
      for (int c = 0; c < 4; ++c) {
        float4v v = *(const float4v*)(p + c * 4);
#pragma unroll
        for (int e = 0; e < 4; ++e) amax = fmaxf(amax, fabsf(v[e]));
      }
    }
#pragma unroll
    for (int d = 1; d < 16; d <<= 1) amax = fmaxf(amax, __shfl_xor(amax, d));
    amax = fmaxf(amax, 1e-20f);
    if (seg == 0) sxr[r16 * 16 + row] = amax * (1.0f / 127.0f);
    const float inv = 127.0f / amax;
    for (int j = 0; j < 16; ++j) {
      const float* p = rowp + j * 256 + seg * 16;
      int4v o;
#pragma unroll
      for (int c = 0; c < 4; ++c) {
        float4v v = *(const float4v*)(p + c * 4);
        unsigned int r = 0;
#pragma unroll
        for (int e = 0; e < 4; ++e) {
          int q = __float2int_rn(v[e] * inv);
          r |= ((unsigned int)(q & 255)) << (8 * e);
        }
        o[c] = (int)r;
      }
      *(int4v*)(sq + row * 272 + seg * 16) = o;
      __syncthreads();
      {
        const int ktl = t >> 6;
        const int l = t & 63;
        int4v vv = *(const int4v*)(sq + (l & 15) * 272 + ktl * 64 + (l >> 4) * 16);
        *(int4v*)(aqf + (((size_t)r16 * NTI + j * 4 + ktl) << 10) + l * 16) = vv;
      }
      __syncthreads();
    }
  } else {
    const int c16 = blockIdx.x - NXB;    // 0..687
    __shared__ float sgl[256];           // [col16][g]
    sgl[t] = scale[(size_t)(c16 * 16 + (t >> 4)) * 16 + (t & 15)];
    __syncthreads();
    const int lane = t & 63;
    const int l15 = lane & 15;
    const int lh = lane >> 4;
    const int ktl = t >> 6;
    float smin = sgl[l15 * 16];
#pragma unroll
    for (int g = 1; g < 16; ++g) smin = fminf(smin, sgl[l15 * 16 + g]);
    if (t < 16) {
      float sm = sgl[t * 16];
#pragma unroll
      for (int g = 1; g < 16; ++g) sm = fminf(sm, sgl[t * 16 + g]);
      swc[c16 * 16 + t] = 1.0f / sm;
    }
    const int* colp = qw + (size_t)(c16 * 16 + l15) * KDIM;
    for (int i = 0; i < 16; ++i) {
      const int kt = i * 4 + ktl;
      const float ratio = smin / sgl[l15 * 16 + i];
      const int* src = colp + kt * 64 + lh * 16;
      int4v v[4];
#pragma unroll
      for (int c = 0; c < 4; ++c) v[c] = *(const int4v*)(src + c * 4);
      int4v o;
#pragma unroll
      for (int c = 0; c < 4; ++c) {
        unsigned int r = 0;
#pragma unroll
        for (int e = 0; e < 4; ++e) {
          int q2 = __float2int_rn((float)v[c][e] * ratio);
          r |= ((unsigned int)(q2 & 255)) << (8 * e);
        }
        o[c] = (int)r;
      }
      *(int4v*)(wqf + (((size_t)c16 * NTI + kt) << 10) + lane * 16) = o;
    }
  }
}

// ---------------- pass 2: 256x128 pure-i8 GEMM, shared fragment-linear LDS ---
// 8 waves (512 thr), wave tile 64x64 (same per-wave profile as r21/r18).
// Per tile: 24KB staged ONCE (A 16 strips + B 8 frags, contiguous-1KB GLDS
// chunks, 3/wave), covering 128 MFMA -> bytes/MFMA halves vs r21. 3-deep LDS
// (72KB, 2 blocks/CU = 4 waves/SIMD). Distance-2 staging; vmcnt(3) steady
// FIFO-exact; tail 3 -> 0. Zero bank conflicts (contiguous fragment reads).
__global__ __launch_bounds__(512, 4) void gemm_i8(
    const char* __restrict__ aqf, const char* __restrict__ wqf,
    const float* __restrict__ sxr, const float* __restrict__ swc,
    const float* __restrict__ bias, float* __restrict__ out)
{
  __shared__ unsigned char lds[73728];   // [3 bufs][24KB: A strips 0-15, B frags 0-7]

  const int t = threadIdx.x;
  const int lane = t & 63;
  const int w = t >> 6;        // wave 0..7
  const int wr = w >> 1;       // 0..3  (A 64-row quarter)
  const int wc = w & 1;        // 0..1  (B 64-col half)
  const int lh = lane >> 4;    // 0..3
  const int l15 = lane & 15;

  // XCD-bijective swizzle: 2752 = 8 * 344
  const int bid = blockIdx.x;
  const int swz = (bid & 7) * (NBM2 * NBNI / 8) + (bid >> 3);
  const int bm = swz / NBNI;
  const int bn = swz % NBNI;

  // staging sources (contiguous 1KB per wave): wave w owns A strips {2w,2w+1}
  // and B frag {w}; per-lane addr = base + lane*16.
  const char* aS0 = aqf + (((size_t)(bm * 16 + 2 * w) * NTI) << 10) + lane * 16;
  const char* aS1 = aS0 + ((size_t)NTI << 10);
  const char* bSw = wqf + (((size_t)(bn * 8 + w) * NTI) << 10) + lane * 16;
  const int aD0 = (2 * w) * 1024, aD1 = (2 * w + 1) * 1024;
  const int bDw = 16384 + w * 1024;

  int4v acci[4][4];
#pragma unroll
  for (int m = 0; m < 4; ++m)
#pragma unroll
    for (int n = 0; n < 4; ++n) acci[m][n] = (int4v){0, 0, 0, 0};

#define STAGE(buf, kt) {                                                       \
  GLDS16(aS0 + ((size_t)(kt) << 10), lds + (buf) * 24576 + aD0);               \
  GLDS16(aS1 + ((size_t)(kt) << 10), lds + (buf) * 24576 + aD1);               \
  GLDS16(bSw + ((size_t)(kt) << 10), lds + (buf) * 24576 + bDw); }

#define RD_A(buf, m) (*(const int4v*)(lds + (buf) * 24576 +                    \
                      (wr * 4 + (m)) * 1024 + lane * 16))
#define RD_B(buf, n) (*(const int4v*)(lds + (buf) * 24576 + 16384 +            \
                      (wc * 4 + (n)) * 1024 + lane * 16))

#define VMW(N) asm volatile("s_waitcnt vmcnt(" N ")" ::: "memory");

// tile kt (buf = kt%3): issue stage(kt+2) into (buf+2)%3; 8 ds_read; 16 MFMA;
// vmcnt drains (kt+1)'s stage (3 loads) before the publish barrier.
#define TILE(buf, kt, DOSTAGE, WAITN, DOBAR) {                                 \
  if (DOSTAGE) STAGE(((buf) + 2) % 3, (kt) + 2);                               \
  __builtin_amdgcn_sched_barrier(0);                                           \
  int4v a[4], b[4];                                                            \
  _Pragma("unroll")                                                            \
  for (int m = 0; m < 4; ++m) a[m] = RD_A(buf, m);                             \
  _Pragma("unroll")                                                            \
  for (int n = 0; n < 4; ++n) b[n] = RD_B(buf, n);                             \
  __builtin_amdgcn_s_setprio(1);                                               \
  _Pragma("unroll")                                                            \
  for (int m = 0; m < 4; ++m)                                                  \
    _Pragma("unroll")                                                          \
    for (int n = 0; n < 4; ++n)                                                \
      acci[m][n] = __builtin_amdgcn_mfma_i32_16x16x64_i8(a[m], b[n],           \
                                                         acci[m][n], 0, 0, 0); \
  __builtin_amdgcn_s_setprio(0);                                               \
  VMW(WAITN)                                                                   \
  if (DOBAR) __builtin_amdgcn_s_barrier(); }

  // prologue: stage tiles 0,1 (3+3 loads/wave); drain tile 0's; publish
  STAGE(0, 0);
  STAGE(1, 1);
  __builtin_amdgcn_sched_barrier(0);
  VMW("3")
  __builtin_amdgcn_s_barrier();

  // steady: tiles 0..59 in 20 groups of 3 (bufs 0,1,2); stage kt+2 <= 61
  for (int kt = 0; kt < NTI - 4; kt += 3) {
    TILE(0, kt,     1, "3", 1)
    TILE(1, kt + 1, 1, "3", 1)
    TILE(2, kt + 2, 1, "3", 1)
  }
  // peeled tail: 60(buf0,stage62), 61(buf1,stage63), 62(buf2,drain), 63(buf0)
  TILE(0, NTI - 4, 1, "3", 1)
  TILE(1, NTI - 3, 1, "3", 1)
  TILE(2, NTI - 2, 0, "0", 1)
  TILE(0, NTI - 1, 0, "0", 0)

  // epilogue: out = acci * sxr[row] * swc[col] + bias
  float swv[4], bias_v[4];
#pragma unroll
  for (int n = 0; n < 4; ++n) {
    const int col = bn * 128 + wc * 64 + n * 16 + l15;
    swv[n] = swc[col];
    bias_v[n] = bias[col];
  }
#pragma unroll
  for (int m = 0; m < 4; ++m) {
    const int row0 = bm * 256 + wr * 64 + m * 16 + lh * 4;
    float4v sxm = *(const float4v*)(sxr + row0);
#pragma unroll
    for (int n = 0; n < 4; ++n) {
      const int col = bn * 128 + wc * 64 + n * 16 + l15;
      const float s_ = swv[n];
      const float bv_ = bias_v[n];
#pragma unroll
      for (int j = 0; j < 4; ++j)
        out[(size_t)(row0 + j) * NDIM + col] =
            (float)acci[m][n][j] * (sxm[j] * s_) + bv_;
    }
  }
#undef TILE
#undef VMW
#undef RD_A
#undef RD_B
#undef STAGE
}

// ---------------- fallback: fused single-pass (round-1 kernel) ----------------
__global__ __launch_bounds__(256, 2) void clinear_fused(
    const float* __restrict__ x,
    const int* __restrict__ qw,
    const float* __restrict__ scale,
    const float* __restrict__ bias,
    float* __restrict__ out)
{
  __shared__ unsigned char ldsA[128 * 64 * 2];
  __shared__ unsigned char ldsB[128 * 64 * 2];

  const int t = threadIdx.x;
  const int lane = t & 63;
  const int wave = t >> 6;
  const int wr = wave >> 1;
  const int wc = wave & 1;

  const int NBN = NDIM / 128;
  const int bid = blockIdx.x;
  const int cpx = ((MDIM / 128) * NBN) >> 3;
  const int swz = (bid & 7) * cpx + (bid >> 3);
  const int bm = swz / NBN;
  const int bn = swz % NBN;

  const int srow = t >> 1;
  const int shalf = t & 1;
  const float* aptr = x  + (size_t)(bm * 128 + srow) * KDIM + shalf * 32;
  const int*   bptr = qw + (size_t)(bn * 128 + srow) * KDIM + shalf * 32;
  const float* sptr = scale + (size_t)(bn * 128 + srow) * (KDIM / 256);
  const int arx = srow & 7;

  f32x4 acc[4][4];
#pragma unroll
  for (int i = 0; i < 4; ++i)
#pragma unroll
    for (int j = 0; j < 4; ++j)
      acc[i][j] = (f32x4){0.f, 0.f, 0.f, 0.f};

  float bias_v[4];
#pragma unroll
  for (int n = 0; n < 4; ++n)
    bias_v[n] = bias[bn * 128 + wc * 64 + n * 16 + (lane & 15)];

  for (int kt = 0; kt < KDIM / 64; ++kt) {
    const int k0 = kt * 64;
    float4v av[8];
    int4v   bv[8];
#pragma unroll
    for (int j = 0; j < 8; ++j) av[j] = *(const float4v*)(aptr + k0 + 4 * j);
#pragma unroll
    for (int j = 0; j < 8; ++j) bv[j] = *(const int4v*)(bptr + k0 + 4 * j);
    const float inv = 1.0f / sptr[k0 >> 8];

    __syncthreads();
#pragma unroll
    for (int c = 0; c < 4; ++c) {
      short8 pa, pb;
#pragma unroll
      for (int e = 0; e < 8; ++e) {
        const int v = c * 8 + e;
        pa[e] = (short)f2bf(av[v >> 2][v & 3]);
        pb[e] = (short)f2bf((float)bv[v >> 2][v & 3] * inv);
      }
      const int cc = shalf * 4 + c;
      *(short8*)(ldsA + srow * 128 + ((cc ^ arx) << 4)) = pa;
      *(short8*)(ldsB + srow * 128 + ((cc ^ arx) << 4)) = pb;
    }
    __syncthreads();

    short8 af[4][2], bfr[4][2];
#pragma unroll
    for (int m = 0; m < 4; ++m) {
      const int r = wr * 64 + m * 16 + (lane & 15);
      const int rx = r & 7;
#pragma unroll
      for (int ks = 0; ks < 2; ++ks) {
        const int ch = ks * 4 + (lane >> 4);
        af[m][ks] = *(const short8*)(ldsA + r * 128 + ((ch ^ rx) << 4));
      }
    }
#pragma unroll
    for (int n = 0; n < 4; ++n) {
      const int r = wc * 64 + n * 16 + (lane & 15);
      const int rx = r & 7;
#pragma unroll
      for (int ks = 0; ks < 2; ++ks) {
        const int ch = ks * 4 + (lane >> 4);
        bfr[n][ks] = *(const short8*)(ldsB + r * 128 + ((ch ^ rx) << 4));
      }
    }
#pragma unroll
    for (int ks = 0; ks < 2; ++ks)
#pragma unroll
      for (int m = 0; m < 4; ++m)
#pragma unroll
        for (int n = 0; n < 4; ++n)
          acc[m][n] = __builtin_amdgcn_mfma_f32_16x16x32_bf16(
              af[m][ks], bfr[n][ks], acc[m][n], 0, 0, 0);
  }

#pragma unroll
  for (int m = 0; m < 4; ++m) {
    const int row0 = bm * 128 + wr * 64 + m * 16 + (lane >> 4) * 4;
#pragma unroll
    for (int n = 0; n < 4; ++n) {
      const int col = bn * 128 + wc * 64 + n * 16 + (lane & 15);
      const float bv_ = bias_v[n];
#pragma unroll
      for (int j = 0; j < 4; ++j)
        out[(size_t)(row0 + j) * NDIM + col] = acc[m][n][j] + bv_;
    }
  }
}

extern "C" void kernel_launch(void* const* d_in, const int* in_sizes, int n_in,
                              void* d_out, int out_size, void* d_ws, size_t ws_size,
                              hipStream_t stream) {
  const float* x     = (const float*)d_in[0];
  const int*   qw    = (const int*)d_in[1];
  const float* scale = (const float*)d_in[2];
  const float* bias  = (const float*)d_in[3];
  float* out = (float*)d_out;

  if (ws_size >= WS_NEED) {
    char*  aqf = (char*)d_ws + AQ_OFF;
    char*  wqf = (char*)d_ws + WQ_OFF;
    float* sxr = (float*)((char*)d_ws + SXR_OFF);
    float* swc = (float*)((char*)d_ws + SWC_OFF);
    hipLaunchKernelGGL(prep_all, dim3(NXB + NC16), dim3(256), 0, stream,
                       x, aqf, sxr, qw, scale, wqf, swc);
    hipLaunchKernelGGL(gemm_i8, dim3(NBM2 * NBNI), dim3(512), 0, stream,
                       aqf, wqf, sxr, swc, bias, out);
  } else {
    hipLaunchKernelGGL(clinear_fused, dim3((MDIM / 128) * (NDIM / 128)), dim3(256),
                       0, stream, x, qw, scale, bias, out);
  }
}